// Round 7
// baseline (709.186 us; speedup 1.0000x reference)
//
#include <hip/hip_runtime.h>

constexpr int IND = 128;
constexpr int HD  = 96;
constexpr int OD  = 64;
constexpr int NL  = 4;

struct F3 { float x, y, z; };

__global__ __launch_bounds__(256) void k_hist(const int* __restrict__ dst, int* __restrict__ deg, int E) {
    int e = blockIdx.x * 256 + threadIdx.x;
    if (e < E) atomicAdd(&deg[dst[e]], 1);
}

__global__ __launch_bounds__(256) void k_scan1(const int* __restrict__ deg, int* __restrict__ bsum, int n) {
    int tid = threadIdx.x;
    int base = blockIdx.x * 1024 + tid * 4;
    int s = 0;
    #pragma unroll
    for (int q = 0; q < 4; ++q) { int i = base + q; if (i < n) s += deg[i]; }
    #pragma unroll
    for (int o = 32; o > 0; o >>= 1) s += __shfl_xor(s, o);
    __shared__ int wsum[4];
    int lane = tid & 63, wid = tid >> 6;
    if (lane == 0) wsum[wid] = s;
    __syncthreads();
    if (tid == 0) bsum[blockIdx.x] = wsum[0] + wsum[1] + wsum[2] + wsum[3];
}

__global__ void k_scan2(const int* __restrict__ bsum, int* __restrict__ boff, int nb,
                        int* __restrict__ row_ptr, int n, int E) {
    int l = threadIdx.x;
    int v = (l < nb) ? bsum[l] : 0;
    int incl = v;
    #pragma unroll
    for (int o = 1; o < 64; o <<= 1) { int t = __shfl_up(incl, o); if (l >= o) incl += t; }
    if (l < nb) boff[l] = incl - v;
    if (l == 0) row_ptr[n] = E;
}

__global__ __launch_bounds__(256) void k_scan3(const int* __restrict__ deg, const int* __restrict__ boff,
                                               int* __restrict__ row_ptr, int n) {
    int tid = threadIdx.x;
    int base = blockIdx.x * 1024 + tid * 4;
    int d[4];
    #pragma unroll
    for (int q = 0; q < 4; ++q) { int i = base + q; d[q] = (i < n) ? deg[i] : 0; }
    int tsum = d[0] + d[1] + d[2] + d[3];
    int incl = tsum;
    #pragma unroll
    for (int o = 1; o < 64; o <<= 1) { int t = __shfl_up(incl, o); if ((tid & 63) >= o) incl += t; }
    __shared__ int wsum[4];
    int lane = tid & 63, wid = tid >> 6;
    if (lane == 63) wsum[wid] = incl;
    __syncthreads();
    int woff = 0;
    for (int w = 0; w < wid; ++w) woff += wsum[w];
    int run = boff[blockIdx.x] + woff + (incl - tsum);
    #pragma unroll
    for (int q = 0; q < 4; ++q) {
        int i = base + q;
        if (i < n) { row_ptr[i] = run; run += d[q]; }
    }
}

// fill CSR: single 8B scatter per edge: sep[slot] = (src[e], e).
__global__ __launch_bounds__(256) void k_fill(const int* __restrict__ src, const int* __restrict__ dst,
                                              const int* __restrict__ row_ptr, int* __restrict__ cursor,
                                              int2* __restrict__ sep, int E) {
    int e = blockIdx.x * 256 + threadIdx.x;
    if (e >= E) return;
    int d = dst[e];
    int pos = atomicAdd(&cursor[d], 1);
    sep[row_ptr[d] + pos] = make_int2(src[e], e);
}

// slot-ordered edge weights for TWO layers (gather reads, sequential writes):
// ewq[i] = (cA0[e], cA1[e]); ewq[E+i] = (cB0[e], cB1[e])
__global__ __launch_bounds__(256) void k_perm2(const int2* __restrict__ sep,
                                               const float* __restrict__ cA0, const float* __restrict__ cA1,
                                               const float* __restrict__ cB0, const float* __restrict__ cB1,
                                               float2* __restrict__ ewq, int E) {
    int i = blockIdx.x * 256 + threadIdx.x;
    if (i >= E) return;
    int e = sep[i].y;
    ewq[i]     = make_float2(cA0[e], cA1[e]);
    ewq[E + i] = make_float2(cB0[e], cB1[e]);
}

// A0[v,:] = sum_e ew0*h[src], A1 likewise. 8 nodes/block, one 32-lane group per
// node, 3 floats/lane, no LDS / no barrier. Unroll-4 keeps 4 row-gathers in flight.
__global__ __launch_bounds__(256) void k_agg(const float* __restrict__ h, const int* __restrict__ row_ptr,
                                             const int2* __restrict__ sep, const float2* __restrict__ ewq,
                                             float* __restrict__ A0, float* __restrict__ A1, int n) {
    int g = blockIdx.x * 8 + (threadIdx.x >> 5);
    int lane = threadIdx.x & 31;
    if (g >= n) return;
    int beg = row_ptr[g], end = row_ptr[g + 1];
    float a0x = 0.f, a0y = 0.f, a0z = 0.f;
    float a1x = 0.f, a1y = 0.f, a1z = 0.f;
    int off = lane * 3;
    int i = beg;
    for (; i + 4 <= end; i += 4) {
        int2 s0 = sep[i], s1 = sep[i + 1], s2 = sep[i + 2], s3 = sep[i + 3];
        float2 w0 = ewq[i], w1 = ewq[i + 1], w2 = ewq[i + 2], w3 = ewq[i + 3];
        F3 v0 = *(const F3*)(h + (size_t)s0.x * HD + off);
        F3 v1 = *(const F3*)(h + (size_t)s1.x * HD + off);
        F3 v2 = *(const F3*)(h + (size_t)s2.x * HD + off);
        F3 v3 = *(const F3*)(h + (size_t)s3.x * HD + off);
        a0x = fmaf(w0.x, v0.x, a0x); a0y = fmaf(w0.x, v0.y, a0y); a0z = fmaf(w0.x, v0.z, a0z);
        a1x = fmaf(w0.y, v0.x, a1x); a1y = fmaf(w0.y, v0.y, a1y); a1z = fmaf(w0.y, v0.z, a1z);
        a0x = fmaf(w1.x, v1.x, a0x); a0y = fmaf(w1.x, v1.y, a0y); a0z = fmaf(w1.x, v1.z, a0z);
        a1x = fmaf(w1.y, v1.x, a1x); a1y = fmaf(w1.y, v1.y, a1y); a1z = fmaf(w1.y, v1.z, a1z);
        a0x = fmaf(w2.x, v2.x, a0x); a0y = fmaf(w2.x, v2.y, a0y); a0z = fmaf(w2.x, v2.z, a0z);
        a1x = fmaf(w2.y, v2.x, a1x); a1y = fmaf(w2.y, v2.y, a1y); a1z = fmaf(w2.y, v2.z, a1z);
        a0x = fmaf(w3.x, v3.x, a0x); a0y = fmaf(w3.x, v3.y, a0y); a0z = fmaf(w3.x, v3.z, a0z);
        a1x = fmaf(w3.y, v3.x, a1x); a1y = fmaf(w3.y, v3.y, a1y); a1z = fmaf(w3.y, v3.z, a1z);
    }
    for (; i < end; ++i) {
        int2 s0 = sep[i];
        float2 w0 = ewq[i];
        F3 v0 = *(const F3*)(h + (size_t)s0.x * HD + off);
        a0x = fmaf(w0.x, v0.x, a0x); a0y = fmaf(w0.x, v0.y, a0y); a0z = fmaf(w0.x, v0.z, a0z);
        a1x = fmaf(w0.y, v0.x, a1x); a1y = fmaf(w0.y, v0.y, a1y); a1z = fmaf(w0.y, v0.z, a1z);
    }
    float* p0 = A0 + (size_t)g * HD + off;
    p0[0] = a0x; p0[1] = a0y; p0[2] = a0z;
    float* p1 = A1 + (size_t)g * HD + off;
    p1[0] = a1x; p1[1] = a1y; p1[2] = a1z;
}

// GEMM: out = [relu]( A0@W0 [+ A1@W1] [+ bias] ).
// 128 rows/block, 256 threads, thread tile 8 rows x NC cols (NC=NO/16).
// Rationale (round-6 counters): per kb-step, 8 ds_read_b128 (~12 LDS-pipe cyc
// each, ONE pipe/CU) must feed the FMAs on 4 SIMDs; at 3 cols/thread LDS demand
// was 2x VALU -> VALUBusy 47%. 6 cols/thread balances 1:1.
// Head-sequential staging reuses one sA (49KB). XOR swizzle (c4 ^= ty&3) kills
// the 4-way bank conflict (row stride 96 = 0 mod 32 across ty).
// out may alias A0p: each block reads only its own rows, staged before store.
template<int K, int NO, bool DUAL, bool RELU, bool BIAS>
__global__ __launch_bounds__(256) void k_gemm(const float* __restrict__ A0p, const float* __restrict__ A1p,
                                              const float* __restrict__ W0p,
                                              const float* __restrict__ bias,
                                              float* __restrict__ out, int n) {
    constexpr int BRO = 128;
    constexpr int KC  = K / 4;        // float4s per row
    constexpr int NC  = NO / 16;      // cols per thread
    __shared__ float sA[BRO * K];
    int tid = threadIdx.x;
    int tx = tid & 15;                // col group: cols NC*tx .. NC*tx+NC-1
    int ty = tid >> 4;                // row group: rows 8*ty .. 8*ty+7
    int ty2 = ty & 3;
    int brow = blockIdx.x * BRO;

    float acc[8][NC];
    #pragma unroll
    for (int r = 0; r < 8; ++r)
        #pragma unroll
        for (int j = 0; j < NC; ++j) acc[r][j] = 0.f;

    #pragma unroll
    for (int head = 0; head < (DUAL ? 2 : 1); ++head) {
        if (head) __syncthreads();    // head0 compute done before restage
        const float* Ah = head ? A1p : A0p;
        for (int j = tid; j < BRO * KC; j += 256) {
            int r = j / KC, c4 = j % KC;
            int gr = brow + r;
            float4 v = make_float4(0.f, 0.f, 0.f, 0.f);
            if (gr < n) v = *(const float4*)(Ah + (size_t)gr * K + 4 * c4);
            int sw = c4 ^ ((r >> 3) & 3);
            *(float4*)&sA[r * K + 4 * sw] = v;
        }
        __syncthreads();

        const float* Wh = W0p + (size_t)head * K * NO;
        #pragma unroll 2
        for (int kb4 = 0; kb4 < KC; ++kb4) {
            float4 a4[8];
            #pragma unroll
            for (int r = 0; r < 8; ++r)
                a4[r] = *(const float4*)&sA[(8 * ty + r) * K + 4 * (kb4 ^ ty2)];
            #pragma unroll
            for (int q = 0; q < 4; ++q) {
                float wv[NC];
                const float* wrow = Wh + (size_t)(4 * kb4 + q) * NO + NC * tx;
                #pragma unroll
                for (int j2 = 0; j2 < NC; j2 += 2) {
                    float2 w2 = *(const float2*)(wrow + j2);
                    wv[j2] = w2.x; wv[j2 + 1] = w2.y;
                }
                #pragma unroll
                for (int r = 0; r < 8; ++r) {
                    const float* ap = (const float*)&a4[r];
                    float av = ap[q];
                    #pragma unroll
                    for (int j2 = 0; j2 < NC; ++j2)
                        acc[r][j2] = fmaf(av, wv[j2], acc[r][j2]);
                }
            }
        }
    }
    #pragma unroll
    for (int r = 0; r < 8; ++r) {
        int gr = brow + 8 * ty + r;
        if (gr < n) {
            float* op = out + (size_t)gr * NO + NC * tx;
            #pragma unroll
            for (int j = 0; j < NC; ++j) {
                float v = acc[r][j];
                if (BIAS) v += bias[NC * tx + j];
                if (RELU) v = fmaxf(v, 0.f);
                op[j] = v;
            }
        }
    }
}

extern "C" void kernel_launch(void* const* d_in, const int* in_sizes, int n_in,
                              void* d_out, int out_size, void* d_ws, size_t ws_size,
                              hipStream_t stream) {
    const float* x     = (const float*)d_in[0];
    const int*   ei    = (const int*)  d_in[1];
    const float* enc_w = (const float*)d_in[2];
    const float* enc_b = (const float*)d_in[3];
    const float* dec_w = (const float*)d_in[4];
    const float* dec_b = (const float*)d_in[5];
    const float* convW = (const float*)d_in[6];
    const float* convE = (const float*)d_in[7];

    const int N = in_sizes[0] / IND;
    const int E = in_sizes[1] / 2;
    const int* src = ei;
    const int* dst = ei + E;
    float* fout = (float*)d_out;

    char* wp = (char*)d_ws;
    auto carve = [&](size_t bytes) -> void* {
        void* p = (void*)wp;
        wp += (bytes + 255) & ~(size_t)255;
        return p;
    };
    int*    deg     = (int*)carve(2 * (size_t)N * 4);   // deg | cursor (one memset)
    int*    cursor  = deg + N;
    int*    row_ptr = (int*)carve(((size_t)N + 1) * 4);
    int*    bsum    = (int*)carve(64 * 4);
    int*    boff    = (int*)carve(64 * 4);
    int2*   sep     = (int2*)carve((size_t)E * 8);
    float*  P0      = (float*)carve((size_t)N * HD * 4);
    float*  P1      = (float*)carve((size_t)N * HD * 4);
    float*  P2      = (float*)carve((size_t)N * HD * 4);
    // ~64.8MB total (round-6-proven footprint)

    // two layers' slot-ordered edge weights live in the out0 region
    // (N*64*4 = 12.8MB >= 2*E*8 = 12.8MB; decoder writes out0 last)
    float2* ewq = (float2*)fout;

    hipMemsetAsync(deg, 0, 2 * (size_t)N * 4, stream);

    int ebl = (E + 255) / 256;
    int nb  = (N + 1023) / 1024;
    k_hist<<<ebl, 256, 0, stream>>>(dst, deg, E);
    k_scan1<<<nb, 256, 0, stream>>>(deg, bsum, N);
    k_scan2<<<1, 64, 0, stream>>>(bsum, boff, nb, row_ptr, N, E);
    k_scan3<<<nb, 256, 0, stream>>>(deg, boff, row_ptr, N);
    k_fill<<<ebl, 256, 0, stream>>>(src, dst, row_ptr, cursor, sep, E);

    int gblG = (N + 127) / 128;
    int gbl8 = (N + 7) / 8;
    float* hfin = fout + (size_t)N * OD;   // out1 region: final h lands here

    // encoder: P0 = relu(x @ enc_w + enc_b)
    k_gemm<IND, HD, false, true, true><<<gblG, 256, 0, stream>>>(x, nullptr, enc_w, enc_b, P0, N);

    // layers: L0 P0->(P1,P2)->P1 ; L1 P1->(P0,P2)->P0 ; L2 ... ; L3 -> hfin
    float* hin[NL]  = { P0, P1, P0, P1 };
    float* ha0[NL]  = { P1, P0, P1, P0 };
    float* hout[NL] = { P1, P0, P1, hfin };
    for (int l = 0; l < NL; ++l) {
        if ((l & 1) == 0) {   // refresh ewq with layers l, l+1
            const float* cA0 = convE + (size_t)(2 * l)     * E;
            const float* cA1 = convE + (size_t)(2 * l + 1) * E;
            const float* cB0 = convE + (size_t)(2 * l + 2) * E;
            const float* cB1 = convE + (size_t)(2 * l + 3) * E;
            k_perm2<<<ebl, 256, 0, stream>>>(sep, cA0, cA1, cB0, cB1, ewq, E);
        }
        const float* Wl = convW + (size_t)l * 2 * HD * HD;
        k_agg<<<gbl8, 256, 0, stream>>>(hin[l], row_ptr, sep, ewq + (size_t)(l & 1) * E, ha0[l], P2, N);
        k_gemm<HD, HD, true, true, false><<<gblG, 256, 0, stream>>>(ha0[l], P2, Wl, nullptr, hout[l], N);
    }
    // decoder: out0 = hfin @ dec_w + dec_b  (overwrites the ewq scratch region)
    k_gemm<HD, OD, false, false, true><<<gblG, 256, 0, stream>>>(hfin, nullptr, dec_w, dec_b, fout, N);
}